// Round 1
// baseline (192.808 us; speedup 1.0000x reference)
//
#include <hip/hip_runtime.h>
#include <math.h>

#define INV_B (1.0f / 8192.0f)

static __device__ __forceinline__ float shflx(float v, int m) {
    return __shfl_xor(v, m, 64);
}

// ---------------------------------------------------------------------------
// K_fp: feature_processor  cf = tanh(relu(x@fW1.T+fb1)@fW2.T+fb2)   (B,4)
// Block 0 additionally computes the 48 fused single-qubit unitaries
// U[l][q] = Rz(t3)*Ry(t2)*Rx(t1) into Uws (8 floats each: re/im of u00,u01,u10,u11).
// Grid: 256 blocks x 256 thr, 32 batch rows per block.
// ---------------------------------------------------------------------------
__global__ __launch_bounds__(256) void k_fp(
        const float* __restrict__ x,
        const float* __restrict__ fW1, const float* __restrict__ fb1,
        const float* __restrict__ fW2, const float* __restrict__ fb2,
        const float* __restrict__ qw,
        float* __restrict__ Uws, float* __restrict__ cfws) {
    const int t = threadIdx.x;

    if (blockIdx.x == 0 && t < 48) {
        const int l = t >> 3, q = t & 7;
        const float* a = qw + l * 24 + q * 3;
        const float h1 = 0.5f * a[0], h2 = 0.5f * a[1], h3 = 0.5f * a[2];
        const float c1 = cosf(h1), s1 = sinf(h1);
        const float c2 = cosf(h2), s2 = sinf(h2);
        const float c3 = cosf(h3), s3 = sinf(h3);
        // M = Ry*Rx
        const float m00r =  c1 * c2, m00i =  s1 * s2;
        const float m01r = -c1 * s2, m01i = -s1 * c2;
        const float m10r =  c1 * s2, m10i = -s1 * c2;
        const float m11r =  c1 * c2, m11i = -s1 * s2;
        // row0 *= e^{-i h3}, row1 *= e^{+i h3}
        float* U = Uws + t * 8;
        U[0] = m00r * c3 + m00i * s3;  U[1] = m00i * c3 - m00r * s3;
        U[2] = m01r * c3 + m01i * s3;  U[3] = m01i * c3 - m01r * s3;
        U[4] = m10r * c3 - m10i * s3;  U[5] = m10i * c3 + m10r * s3;
        U[6] = m11r * c3 - m11i * s3;  U[7] = m11i * c3 + m11r * s3;
    }

    __shared__ float xs[256][33];       // transposed: xs[col][row], pad 33 -> conflict-free
    const int r0 = blockIdx.x * 32;
    #pragma unroll
    for (int k = 0; k < 8; ++k) {
        const int idx4 = t + k * 256;   // float4 tile index 0..2047
        const int row = idx4 >> 6;      // 64 float4 per row
        const int c4  = idx4 & 63;
        const float4 xv = ((const float4*)(x + (long)(r0 + row) * 256))[c4];
        xs[c4 * 4 + 0][row] = xv.x; xs[c4 * 4 + 1][row] = xv.y;
        xs[c4 * 4 + 2][row] = xv.z; xs[c4 * 4 + 3][row] = xv.w;
    }
    __syncthreads();

    const int e = t & 31, jg = t >> 5;  // row within tile, output j-group (8 j each)
    const int jb = jg * 8;
    float acc[8] = {0, 0, 0, 0, 0, 0, 0, 0};
    for (int i = 0; i < 256; i += 4) {
        const float x0 = xs[i][e], x1 = xs[i + 1][e];
        const float x2 = xs[i + 2][e], x3 = xs[i + 3][e];
        #pragma unroll
        for (int jj = 0; jj < 8; ++jj) {
            const float4 w = *(const float4*)(fW1 + (jb + jj) * 256 + i);
            acc[jj] += w.x * x0 + w.y * x1 + w.z * x2 + w.w * x3;
        }
    }
    float p[4] = {0, 0, 0, 0};
    #pragma unroll
    for (int jj = 0; jj < 8; ++jj) {
        float v = fmaxf(acc[jj] + fb1[jb + jj], 0.f);   // relu
        #pragma unroll
        for (int k2 = 0; k2 < 4; ++k2) p[k2] += fW2[k2 * 64 + jb + jj] * v;
    }
    __shared__ float part[8][32][4];
    part[jg][e][0] = p[0]; part[jg][e][1] = p[1];
    part[jg][e][2] = p[2]; part[jg][e][3] = p[3];
    __syncthreads();
    if (t < 128) {
        const int ee = t >> 2, k2 = t & 3;
        float s = fb2[k2];
        #pragma unroll
        for (int g = 0; g < 8; ++g) s += part[g][ee][k2];
        cfws[(long)(r0 + ee) * 4 + k2] = tanhf(s);
    }
}

// ---------------------------------------------------------------------------
// K_q: quantum circuit, one wave per batch element.
// Lane holds amps i = 4*lane + r (r=0..3): bits1:0 = reg, bits7:2 = lane bits 5:0.
// Wire w acts on bit (7-w).  Produces h = aW@q + ab + cf (B,4) plus batch
// stats sum(h), sum(h h^T) into 32 atomic slots for the analytic BN1.
// Grid: 2048 blocks x 256 thr (4 waves = 4 elements per block).
// ---------------------------------------------------------------------------
__global__ __launch_bounds__(256) void k_q(
        const float* __restrict__ x, const float* __restrict__ Uws,
        const float* __restrict__ aW, const float* __restrict__ ab,
        const float* __restrict__ cfws,
        float* __restrict__ hws, float* __restrict__ acc1) {
    const int t = threadIdx.x;
    const int lane = t & 63, wv = t >> 6;
    const int row = blockIdx.x * 4 + wv;

    const float4 xr = ((const float4*)(x + (long)row * 256))[lane];
    float nn = xr.x * xr.x + xr.y * xr.y + xr.z * xr.z + xr.w * xr.w;
    #pragma unroll
    for (int m = 1; m < 64; m <<= 1) nn += shflx(nn, m);
    const float sc = 1.0f / sqrtf(nn);

    float ar[4] = {xr.x * sc, xr.y * sc, xr.z * sc, xr.w * sc};
    float ai[4] = {0.f, 0.f, 0.f, 0.f};

    // CNOT helpers
    auto cnot_ll = [&](int lc, int m) {    // control lane-bit lc, target = lane xor m
        const int c = (lane >> lc) & 1;
        #pragma unroll
        for (int r = 0; r < 4; ++r) {
            const float pr = shflx(ar[r], m), pi = shflx(ai[r], m);
            ar[r] = c ? pr : ar[r];
            ai[r] = c ? pi : ai[r];
        }
    };
    auto cswap_regs = [&](int c) {         // if c: swap (r0,r2) and (r1,r3)
        const float t0r = ar[0], t0i = ai[0], t1r = ar[1], t1i = ai[1];
        ar[0] = c ? ar[2] : ar[0]; ai[0] = c ? ai[2] : ai[0];
        ar[2] = c ? t0r : ar[2];   ai[2] = c ? t0i : ai[2];
        ar[1] = c ? ar[3] : ar[1]; ai[1] = c ? ai[3] : ai[1];
        ar[3] = c ? t1r : ar[3];   ai[3] = c ? t1i : ai[3];
    };

    #pragma unroll 1
    for (int l = 0; l < 6; ++l) {
        const float* Ul = Uws + l * 64;
        // wires 0..5 -> bits 7..2 -> lane bits 5..0 (cross-lane)
        #pragma unroll
        for (int q = 0; q < 6; ++q) {
            const float* U = Ul + q * 8;
            const float u00r = U[0], u00i = U[1], u01r = U[2], u01i = U[3];
            const float u10r = U[4], u10i = U[5], u11r = U[6], u11i = U[7];
            const int lb = 5 - q;
            const int mask = 1 << lb;
            const int bit = (lane >> lb) & 1;
            const float csr = bit ? u11r : u00r, csi = bit ? u11i : u00i;
            const float cpr = bit ? u10r : u01r, cpi = bit ? u10i : u01i;
            #pragma unroll
            for (int r = 0; r < 4; ++r) {
                const float pr = shflx(ar[r], mask), pi = shflx(ai[r], mask);
                const float nr = csr * ar[r] - csi * ai[r] + cpr * pr - cpi * pi;
                const float ni = csr * ai[r] + csi * ar[r] + cpr * pi + cpi * pr;
                ar[r] = nr; ai[r] = ni;
            }
        }
        { // wire 6 -> bit 1: pairs (0,2),(1,3)
            const float* U = Ul + 48;
            const float u00r = U[0], u00i = U[1], u01r = U[2], u01i = U[3];
            const float u10r = U[4], u10i = U[5], u11r = U[6], u11i = U[7];
            const float n0r = u00r*ar[0]-u00i*ai[0] + u01r*ar[2]-u01i*ai[2];
            const float n0i = u00r*ai[0]+u00i*ar[0] + u01r*ai[2]+u01i*ar[2];
            const float n2r = u10r*ar[0]-u10i*ai[0] + u11r*ar[2]-u11i*ai[2];
            const float n2i = u10r*ai[0]+u10i*ar[0] + u11r*ai[2]+u11i*ar[2];
            const float n1r = u00r*ar[1]-u00i*ai[1] + u01r*ar[3]-u01i*ai[3];
            const float n1i = u00r*ai[1]+u00i*ar[1] + u01r*ai[3]+u01i*ar[3];
            const float n3r = u10r*ar[1]-u10i*ai[1] + u11r*ar[3]-u11i*ai[3];
            const float n3i = u10r*ai[1]+u10i*ar[1] + u11r*ai[3]+u11i*ar[3];
            ar[0]=n0r; ai[0]=n0i; ar[2]=n2r; ai[2]=n2i;
            ar[1]=n1r; ai[1]=n1i; ar[3]=n3r; ai[3]=n3i;
        }
        { // wire 7 -> bit 0: pairs (0,1),(2,3)
            const float* U = Ul + 56;
            const float u00r = U[0], u00i = U[1], u01r = U[2], u01i = U[3];
            const float u10r = U[4], u10i = U[5], u11r = U[6], u11i = U[7];
            const float n0r = u00r*ar[0]-u00i*ai[0] + u01r*ar[1]-u01i*ai[1];
            const float n0i = u00r*ai[0]+u00i*ar[0] + u01r*ai[1]+u01i*ar[1];
            const float n1r = u10r*ar[0]-u10i*ai[0] + u11r*ar[1]-u11i*ai[1];
            const float n1i = u10r*ai[0]+u10i*ar[0] + u11r*ai[1]+u11i*ar[1];
            const float n2r = u00r*ar[2]-u00i*ai[2] + u01r*ar[3]-u01i*ai[3];
            const float n2i = u00r*ai[2]+u00i*ar[2] + u01r*ai[3]+u01i*ar[3];
            const float n3r = u10r*ar[2]-u10i*ai[2] + u11r*ar[3]-u11i*ai[3];
            const float n3i = u10r*ai[2]+u10i*ar[2] + u11r*ai[3]+u11i*ar[3];
            ar[0]=n0r; ai[0]=n0i; ar[1]=n1r; ai[1]=n1i;
            ar[2]=n2r; ai[2]=n2i; ar[3]=n3r; ai[3]=n3i;
        }
        // CNOT chain: wires (0,1)(1,2)(2,3)(3,4)(4,5)(5,6)(6,7)(7,0)(0,2)(2,4)(4,6)
        cnot_ll(5, 16);                 // (0,1): bits (7,6)
        cnot_ll(4, 8);                  // (1,2): bits (6,5)
        cnot_ll(3, 4);                  // (2,3): bits (5,4)
        cnot_ll(2, 2);                  // (3,4): bits (4,3)
        cnot_ll(1, 1);                  // (4,5): bits (3,2)
        cswap_regs(lane & 1);           // (5,6): ctrl bit2 (lane bit0), tgt bit1
        {                               // (6,7): ctrl bit1, tgt bit0 -> swap r2<->r3
            const float tr = ar[2]; ar[2] = ar[3]; ar[3] = tr;
            const float ti = ai[2]; ai[2] = ai[3]; ai[3] = ti;
        }
        {                               // (7,0): ctrl bit0 (regs 1,3), tgt bit7 (lane^32)
            ar[1] = shflx(ar[1], 32); ai[1] = shflx(ai[1], 32);
            ar[3] = shflx(ar[3], 32); ai[3] = shflx(ai[3], 32);
        }
        cnot_ll(5, 8);                  // (0,2): bits (7,5)
        cnot_ll(3, 2);                  // (2,4): bits (5,3)
        cswap_regs((lane >> 1) & 1);    // (4,6): ctrl bit3 (lane bit1), tgt bit1
    }

    // probabilities and Z expectations on wires 0..3 (lane bits 5..2)
    float p = 0.f;
    #pragma unroll
    for (int r = 0; r < 4; ++r) p += ar[r] * ar[r] + ai[r] * ai[r];
    float qe[4];
    #pragma unroll
    for (int w = 0; w < 4; ++w) {
        float v = ((lane >> (5 - w)) & 1) ? -p : p;
        #pragma unroll
        for (int m = 1; m < 64; m <<= 1) v += shflx(v, m);
        qe[w] = v;
    }
    float h[4];
    #pragma unroll
    for (int k = 0; k < 4; ++k) {
        float s = ab[k];
        #pragma unroll
        for (int j = 0; j < 4; ++j) s += aW[k * 4 + j] * qe[j];
        h[k] = s + cfws[(long)row * 4 + k];
    }
    if (lane < 4) hws[(long)row * 4 + lane] = h[lane];

    __shared__ float wsum[4][20];
    if (lane == 0) {
        #pragma unroll
        for (int k = 0; k < 4; ++k) wsum[wv][k] = h[k];
        #pragma unroll
        for (int j = 0; j < 4; ++j)
            #pragma unroll
            for (int k = 0; k < 4; ++k) wsum[wv][4 + j * 4 + k] = h[j] * h[k];
    }
    __syncthreads();
    if (t < 20) {
        const float v = wsum[0][t] + wsum[1][t] + wsum[2][t] + wsum[3][t];
        atomicAdd(acc1 + (blockIdx.x & 31) * 20 + t, v);
    }
}

// ---------------------------------------------------------------------------
// K2: BN1 (analytic from sum_h/sum_hh) + relu + layer2 -> z2; z2 batch stats.
// Grid: 128 blocks x 64 thr, one element per thread.
// ---------------------------------------------------------------------------
__global__ __launch_bounds__(64) void k_mid(
        const float* __restrict__ hws, const float* __restrict__ acc1,
        const float* __restrict__ cW1, const float* __restrict__ cb1,
        const float* __restrict__ g1, const float* __restrict__ be1,
        const float* __restrict__ cW2, const float* __restrict__ cb2,
        float* __restrict__ z2ws, float* __restrict__ acc2) {
    const int t = threadIdx.x;
    __shared__ float sA[20];
    __shared__ float m1s[32], is1[32];
    if (t < 20) {
        float s = 0.f;
        for (int sl = 0; sl < 32; ++sl) s += acc1[sl * 20 + t];
        sA[t] = s;
    }
    __syncthreads();
    if (t < 32) {
        float mu[4];
        #pragma unroll
        for (int k = 0; k < 4; ++k) mu[k] = sA[k] * INV_B;
        float w[4];
        float m = cb1[t];
        #pragma unroll
        for (int k = 0; k < 4; ++k) { w[k] = cW1[t * 4 + k]; m += w[k] * mu[k]; }
        float var = 0.f;
        #pragma unroll
        for (int a2 = 0; a2 < 4; ++a2)
            #pragma unroll
            for (int b2 = 0; b2 < 4; ++b2)
                var += w[a2] * w[b2] * (sA[4 + a2 * 4 + b2] * INV_B - mu[a2] * mu[b2]);
        m1s[t] = m;
        is1[t] = 1.0f / sqrtf(var + 1e-5f);
    }
    __syncthreads();

    const long e = (long)blockIdx.x * 64 + t;
    const float4 h4 = ((const float4*)hws)[e];
    const float h[4] = {h4.x, h4.y, h4.z, h4.w};
    float a1[32];
    #pragma unroll
    for (int j = 0; j < 32; ++j) {
        float z = cb1[j];
        #pragma unroll
        for (int k = 0; k < 4; ++k) z += cW1[j * 4 + k] * h[k];
        a1[j] = fmaxf((z - m1s[j]) * is1[j] * g1[j] + be1[j], 0.f);
    }
    float z2[16];
    #pragma unroll
    for (int k = 0; k < 16; ++k) {
        float s = cb2[k];
        #pragma unroll
        for (int j = 0; j < 32; ++j) s += cW2[k * 32 + j] * a1[j];
        z2[k] = s;
    }
    float4* zp = (float4*)(z2ws + e * 16);
    zp[0] = make_float4(z2[0], z2[1], z2[2], z2[3]);
    zp[1] = make_float4(z2[4], z2[5], z2[6], z2[7]);
    zp[2] = make_float4(z2[8], z2[9], z2[10], z2[11]);
    zp[3] = make_float4(z2[12], z2[13], z2[14], z2[15]);

    float sv[16], sq[16];
    #pragma unroll
    for (int k = 0; k < 16; ++k) { sv[k] = z2[k]; sq[k] = z2[k] * z2[k]; }
    #pragma unroll
    for (int m = 1; m < 64; m <<= 1) {
        #pragma unroll
        for (int k = 0; k < 16; ++k) {
            sv[k] += shflx(sv[k], m);
            sq[k] += shflx(sq[k], m);
        }
    }
    if (t == 0) {
        float* dst = acc2 + (blockIdx.x & 31) * 32;
        #pragma unroll
        for (int k = 0; k < 16; ++k) atomicAdd(dst + k, sv[k]);
        #pragma unroll
        for (int k = 0; k < 16; ++k) atomicAdd(dst + 16 + k, sq[k]);
    }
}

// ---------------------------------------------------------------------------
// K3: BN2 + relu + layer3(relu) + layer4 + sigmoid -> out (B,1)
// Grid: 128 blocks x 64 thr.
// ---------------------------------------------------------------------------
__global__ __launch_bounds__(64) void k_out(
        const float* __restrict__ z2ws, const float* __restrict__ acc2,
        const float* __restrict__ g2, const float* __restrict__ be2,
        const float* __restrict__ cW3, const float* __restrict__ cb3,
        const float* __restrict__ cW4, const float* __restrict__ cb4,
        float* __restrict__ out) {
    const int t = threadIdx.x;
    __shared__ float sB[32];
    __shared__ float m2s[16], is2[16];
    if (t < 32) {
        float s = 0.f;
        for (int sl = 0; sl < 32; ++sl) s += acc2[sl * 32 + t];
        sB[t] = s;
    }
    __syncthreads();
    if (t < 16) {
        const float m = sB[t] * INV_B;
        const float var = sB[16 + t] * INV_B - m * m;
        m2s[t] = m;
        is2[t] = 1.0f / sqrtf(var + 1e-5f);
    }
    __syncthreads();

    const long e = (long)blockIdx.x * 64 + t;
    const float4* zp = (const float4*)(z2ws + e * 16);
    const float4 v0 = zp[0], v1 = zp[1], v2 = zp[2], v3 = zp[3];
    const float z2[16] = {v0.x, v0.y, v0.z, v0.w, v1.x, v1.y, v1.z, v1.w,
                          v2.x, v2.y, v2.z, v2.w, v3.x, v3.y, v3.z, v3.w};
    float a2[16];
    #pragma unroll
    for (int k = 0; k < 16; ++k)
        a2[k] = fmaxf((z2[k] - m2s[k]) * is2[k] * g2[k] + be2[k], 0.f);
    float z3[8];
    #pragma unroll
    for (int j = 0; j < 8; ++j) {
        float s = cb3[j];
        #pragma unroll
        for (int k = 0; k < 16; ++k) s += cW3[j * 16 + k] * a2[k];
        z3[j] = fmaxf(s, 0.f);
    }
    float y = cb4[0];
    #pragma unroll
    for (int j = 0; j < 8; ++j) y += cW4[j] * z3[j];
    out[e] = 1.0f / (1.0f + expf(-y));
}

// ---------------------------------------------------------------------------
extern "C" void kernel_launch(void* const* d_in, const int* in_sizes, int n_in,
                              void* d_out, int out_size, void* d_ws, size_t ws_size,
                              hipStream_t stream) {
    (void)in_sizes; (void)n_in; (void)out_size; (void)ws_size;
    const float* x   = (const float*)d_in[0];
    const float* qw  = (const float*)d_in[1];
    const float* aW  = (const float*)d_in[2];
    const float* ab  = (const float*)d_in[3];
    const float* fW1 = (const float*)d_in[4];
    const float* fb1 = (const float*)d_in[5];
    const float* fW2 = (const float*)d_in[6];
    const float* fb2 = (const float*)d_in[7];
    const float* cW1 = (const float*)d_in[8];
    const float* cb1 = (const float*)d_in[9];
    const float* g1  = (const float*)d_in[10];
    const float* be1 = (const float*)d_in[11];
    const float* cW2 = (const float*)d_in[12];
    const float* cb2 = (const float*)d_in[13];
    const float* g2  = (const float*)d_in[14];
    const float* be2 = (const float*)d_in[15];
    const float* cW3 = (const float*)d_in[16];
    const float* cb3 = (const float*)d_in[17];
    const float* cW4 = (const float*)d_in[18];
    const float* cb4 = (const float*)d_in[19];

    float* ws   = (float*)d_ws;
    float* acc1 = ws;              // 32 slots x 20 floats = 640
    float* acc2 = ws + 1024;       // 32 slots x 32 floats = 1024
    float* Uws  = ws + 2048;       // 48 x 8 = 384
    float* cfws = ws + 4096;       // 8192 x 4 = 32768
    float* hws  = ws + 40960;      // 8192 x 4 = 32768
    float* z2ws = ws + 81920;      // 8192 x 16 = 131072   (total ~832 KB)

    hipMemsetAsync(d_ws, 0, 2048 * sizeof(float), stream);   // zero acc1+acc2
    k_fp <<<256, 256, 0, stream>>>(x, fW1, fb1, fW2, fb2, qw, Uws, cfws);
    k_q  <<<2048, 256, 0, stream>>>(x, Uws, aW, ab, cfws, hws, acc1);
    k_mid<<<128, 64, 0, stream>>>(hws, acc1, cW1, cb1, g1, be1, cW2, cb2, z2ws, acc2);
    k_out<<<128, 64, 0, stream>>>(z2ws, acc2, g2, be2, cW3, cb3, cW4, cb4, (float*)d_out);
}

// Round 3
// 157.170 us; speedup vs baseline: 1.2267x; 1.2267x over previous
//
#include <hip/hip_runtime.h>
#include <math.h>

#define INV_B (1.0f / 8192.0f)

// ---------------------------------------------------------------------------
// Compile-time GF(2) tracking of the CNOT network.
// Index i (8 bits): wire w <-> bit (7-w).  Storage: i = 4*lane + reg.
// State kept as s[i] = psi[M i]; CNOT(c,t) updates M' = C M (row bt ^= row bc)
// and N = M^{-1} via N' = N C (col bc ^= col bt).
// Gate on wire w (bit b): partner mask = Ncol[b], row parity mask = Mrow[b].
// Layer-0 masks are identity -> reproduces the R0-verified direct circuit.
// ---------------------------------------------------------------------------
struct QTables {
    int xm[6][8];   // xor (partner) mask per (layer, wire)
    int rm[6][8];   // row parity mask per (layer, wire)
    int meas[4];    // measurement parity masks, wires 0..3
};
constexpr QTables make_tables() {
    QTables T{};
    int Mrow[8] = {}, Ncol[8] = {};
    for (int b = 0; b < 8; ++b) { Mrow[b] = 1 << b; Ncol[b] = 1 << b; }
    // CNOT chain in bit indices: wires (0,1)(1,2)..(6,7)(7,0)(0,2)(2,4)(4,6)
    constexpr int bc[11] = {7,6,5,4,3,2,1,0,7,5,3};
    constexpr int bt[11] = {6,5,4,3,2,1,0,7,5,3,1};
    for (int l = 0; l < 6; ++l) {
        for (int w = 0; w < 8; ++w) { T.xm[l][w] = Ncol[7 - w]; T.rm[l][w] = Mrow[7 - w]; }
        for (int k = 0; k < 11; ++k) { Mrow[bt[k]] ^= Mrow[bc[k]]; Ncol[bc[k]] ^= Ncol[bt[k]]; }
    }
    for (int w = 0; w < 4; ++w) T.meas[w] = Mrow[7 - w];
    return T;
}
constexpr QTables TB = make_tables();

// xor-shuffle along lane mask ML; masks 1..3 run on VALU via DPP quad_perm.
template<int ML>
static __device__ __forceinline__ float lanex(float v) {
    if constexpr (ML == 0) { return v; }
    else if constexpr (ML == 1) { return __int_as_float(__builtin_amdgcn_update_dpp(0, __float_as_int(v), 0xB1, 0xF, 0xF, true)); }
    else if constexpr (ML == 2) { return __int_as_float(__builtin_amdgcn_update_dpp(0, __float_as_int(v), 0x4E, 0xF, 0xF, true)); }
    else if constexpr (ML == 3) { return __int_as_float(__builtin_amdgcn_update_dpp(0, __float_as_int(v), 0x1B, 0xF, 0xF, true)); }
    else { return __shfl_xor(v, ML, 64); }
}

static __device__ __forceinline__ float bsum64(float v) {
    v += lanex<1>(v); v += lanex<2>(v);
    v += __shfl_xor(v, 4, 64);  v += __shfl_xor(v, 8, 64);
    v += __shfl_xor(v, 16, 64); v += __shfl_xor(v, 32, 64);
    return v;
}

// Fused SU(2) gate: u11 = conj(u00), u10 = -conj(u01).
// bit = parity((4*lane+r) & RM):  bit=0 -> new = u00*cur + u01*par
//                                 bit=1 -> new = u10*par + u11*cur
template<int XM, int RM>
static __device__ __forceinline__ void gate(float (&ar)[4], float (&ai)[4], const int lane,
                                            const float u00r, const float u00i,
                                            const float u01r, const float u01i) {
    constexpr int ML = XM >> 2, MR = XM & 3;
    constexpr int RL = RM >> 2, RR = RM & 3;
    const int pl = __popc(lane & RL) & 1;
    const float csi0 = pl ? -u00i : u00i;
    const float cpr0 = pl ? -u01r : u01r;
    const float csi1 = -csi0, cpr1 = -cpr0;
    float pr[4], pi[4];
    #pragma unroll
    for (int r = 0; r < 4; ++r) {
        pr[r] = lanex<ML>(ar[r ^ MR]);
        pi[r] = lanex<ML>(ai[r ^ MR]);
    }
    #pragma unroll
    for (int r = 0; r < 4; ++r) {
        const int pb = __builtin_popcount(r & RR) & 1;   // folds at compile time
        const float csi = pb ? csi1 : csi0;
        const float cpr = pb ? cpr1 : cpr0;
        const float nr = u00r * ar[r] - csi * ai[r] + cpr * pr[r] - u01i * pi[r];
        const float ni = u00r * ai[r] + csi * ar[r] + cpr * pi[r] + u01i * pr[r];
        ar[r] = nr; ai[r] = ni;
    }
}

// ---------------------------------------------------------------------------
// k_pre: transpose fW1 -> fT (float4-friendly), build the 48 fused single-
// qubit unitaries into U (4 floats each: u00r,u00i,u01r,u01i; SU(2) implies
// the second row), and zero the BN accumulators.  Grid: 64 x 256.
// ---------------------------------------------------------------------------
__global__ __launch_bounds__(256) void k_pre(
        const float* __restrict__ fW1, const float* __restrict__ qw,
        float* __restrict__ U, float* __restrict__ fT, float* __restrict__ accz) {
    const int t = threadIdx.x, b = blockIdx.x;
    const int e = b * 256 + t;                  // 16384 elements of fW1
    const int j = e >> 8, k = e & 255;
    fT[(k >> 2) * 256 + j * 4 + (k & 3)] = fW1[e];
    if (e < 2048) accz[e] = 0.f;                // acc1 + acc2
    if (b == 0 && t < 48) {
        const int l = t >> 3, q = t & 7;
        const float* a = qw + l * 24 + q * 3;
        const float h1 = 0.5f * a[0], h2 = 0.5f * a[1], h3 = 0.5f * a[2];
        const float c1 = cosf(h1), s1 = sinf(h1);
        const float c2 = cosf(h2), s2 = sinf(h2);
        const float c3 = cosf(h3), s3 = sinf(h3);
        const float m00r =  c1 * c2, m00i =  s1 * s2;   // (Ry*Rx) row 0
        const float m01r = -c1 * s2, m01i = -s1 * c2;
        float4 u;
        u.x = m00r * c3 + m00i * s3;  u.y = m00i * c3 - m00r * s3;   // u00 e^{-i h3}
        u.z = m01r * c3 + m01i * s3;  u.w = m01i * c3 - m01r * s3;   // u01 e^{-i h3}
        ((float4*)U)[t] = u;
    }
}

// ---------------------------------------------------------------------------
// k_main: feature processor + quantum circuit + h + BN1 moment atomics.
// One wave per batch row; 2048 blocks x 256 thr (4 waves).
// ---------------------------------------------------------------------------
__global__ __launch_bounds__(256) void k_main(
        const float* __restrict__ x, const float* __restrict__ U,
        const float* __restrict__ fT,
        const float* __restrict__ fb1, const float* __restrict__ fW2,
        const float* __restrict__ fb2,
        const float* __restrict__ aW, const float* __restrict__ ab,
        float* __restrict__ hws, float* __restrict__ acc1) {
    const int t = threadIdx.x, lane = t & 63, wv = t >> 6;
    const int b = blockIdx.x;
    const int row = b * 4 + wv;

    const float4 xr = ((const float4*)(x + (long)row * 256))[lane];

    // ---- feature: lane j computes z1[j] = dot(x_row, fW1[j,:]); x bcast by readlane
    const float4* fT4 = (const float4*)fT;
    float z1 = 0.f;
    #pragma unroll 8
    for (int kk = 0; kk < 64; ++kk) {
        const float4 w4 = fT4[kk * 64 + lane];
        const float x0 = __int_as_float(__builtin_amdgcn_readlane(__float_as_int(xr.x), kk));
        const float x1 = __int_as_float(__builtin_amdgcn_readlane(__float_as_int(xr.y), kk));
        const float x2 = __int_as_float(__builtin_amdgcn_readlane(__float_as_int(xr.z), kk));
        const float x3 = __int_as_float(__builtin_amdgcn_readlane(__float_as_int(xr.w), kk));
        z1 += w4.x * x0 + w4.y * x1 + w4.z * x2 + w4.w * x3;
    }
    const float v1 = fmaxf(z1 + fb1[lane], 0.f);
    float cf[4];
    #pragma unroll
    for (int c = 0; c < 4; ++c) {
        const float s = bsum64(v1 * fW2[c * 64 + lane]);
        cf[c] = tanhf(s + fb2[c]);
    }

    // ---- quantum: unnormalized amps (normalization folded into qe = sum± / sum)
    float ar[4] = {xr.x, xr.y, xr.z, xr.w};
    float ai[4] = {0.f, 0.f, 0.f, 0.f};
    const float4* U4 = (const float4*)U;

#define GATE(L, W) { const float4 u = U4[(L) * 8 + (W)]; \
                     gate<TB.xm[L][W], TB.rm[L][W]>(ar, ai, lane, u.x, u.y, u.z, u.w); }
#define LAYER(L) GATE(L,0) GATE(L,1) GATE(L,2) GATE(L,3) GATE(L,4) GATE(L,5) GATE(L,6) GATE(L,7)
    LAYER(0) LAYER(1) LAYER(2) LAYER(3) LAYER(4) LAYER(5)
#undef LAYER
#undef GATE

    float pv[4];
    #pragma unroll
    for (int r = 0; r < 4; ++r) pv[r] = ar[r] * ar[r] + ai[r] * ai[r];
    float S = pv[0] + pv[1] + pv[2] + pv[3];
    float qs[4];
    #pragma unroll
    for (int w = 0; w < 4; ++w) {
        const int mm = TB.meas[w];
        const int plm = __popc(lane & (mm >> 2)) & 1;
        float s = 0.f;
        #pragma unroll
        for (int r = 0; r < 4; ++r) {
            const int sgn = plm ^ (__builtin_popcount(r & (mm & 3)) & 1);
            s += sgn ? -pv[r] : pv[r];
        }
        qs[w] = s;
    }
    S = bsum64(S);
    const float inv = 1.0f / S;
    float qe[4];
    #pragma unroll
    for (int w = 0; w < 4; ++w) qe[w] = bsum64(qs[w]) * inv;

    float h[4];
    #pragma unroll
    for (int k = 0; k < 4; ++k) {
        float s = ab[k] + cf[k];
        #pragma unroll
        for (int j = 0; j < 4; ++j) s += aW[k * 4 + j] * qe[j];
        h[k] = s;
    }
    if (lane == 0)
        ((float4*)hws)[row] = make_float4(h[0], h[1], h[2], h[3]);

    __shared__ float wsum[4][20];
    if (lane == 0) {
        #pragma unroll
        for (int k = 0; k < 4; ++k) wsum[wv][k] = h[k];
        #pragma unroll
        for (int j = 0; j < 4; ++j)
            #pragma unroll
            for (int k = 0; k < 4; ++k) wsum[wv][4 + j * 4 + k] = h[j] * h[k];
    }
    __syncthreads();
    if (t < 20)
        atomicAdd(acc1 + (b & 31) * 20 + t,
                  wsum[0][t] + wsum[1][t] + wsum[2][t] + wsum[3][t]);
}

// ---------------------------------------------------------------------------
// k_mid: analytic BN1 + relu + layer2 -> z2; z2 batch stats.  (R0-verified)
// Grid: 128 x 64.
// ---------------------------------------------------------------------------
__global__ __launch_bounds__(64) void k_mid(
        const float* __restrict__ hws, const float* __restrict__ acc1,
        const float* __restrict__ cW1, const float* __restrict__ cb1,
        const float* __restrict__ g1, const float* __restrict__ be1,
        const float* __restrict__ cW2, const float* __restrict__ cb2,
        float* __restrict__ z2ws, float* __restrict__ acc2) {
    const int t = threadIdx.x;
    __shared__ float sA[20];
    __shared__ float m1s[32], is1[32];
    if (t < 20) {
        float s = 0.f;
        for (int sl = 0; sl < 32; ++sl) s += acc1[sl * 20 + t];
        sA[t] = s;
    }
    __syncthreads();
    if (t < 32) {
        float mu[4], w[4];
        #pragma unroll
        for (int k = 0; k < 4; ++k) mu[k] = sA[k] * INV_B;
        float m = cb1[t];
        #pragma unroll
        for (int k = 0; k < 4; ++k) { w[k] = cW1[t * 4 + k]; m += w[k] * mu[k]; }
        float var = 0.f;
        #pragma unroll
        for (int a2 = 0; a2 < 4; ++a2)
            #pragma unroll
            for (int b2 = 0; b2 < 4; ++b2)
                var += w[a2] * w[b2] * (sA[4 + a2 * 4 + b2] * INV_B - mu[a2] * mu[b2]);
        m1s[t] = m;
        is1[t] = 1.0f / sqrtf(var + 1e-5f);
    }
    __syncthreads();

    const long e = (long)blockIdx.x * 64 + t;
    const float4 h4 = ((const float4*)hws)[e];
    const float h[4] = {h4.x, h4.y, h4.z, h4.w};
    float a1[32];
    #pragma unroll
    for (int j = 0; j < 32; ++j) {
        float z = cb1[j];
        #pragma unroll
        for (int k = 0; k < 4; ++k) z += cW1[j * 4 + k] * h[k];
        a1[j] = fmaxf((z - m1s[j]) * is1[j] * g1[j] + be1[j], 0.f);
    }
    float z2[16];
    #pragma unroll
    for (int k = 0; k < 16; ++k) {
        float s = cb2[k];
        #pragma unroll
        for (int j = 0; j < 32; ++j) s += cW2[k * 32 + j] * a1[j];
        z2[k] = s;
    }
    float4* zp = (float4*)(z2ws + e * 16);
    zp[0] = make_float4(z2[0], z2[1], z2[2], z2[3]);
    zp[1] = make_float4(z2[4], z2[5], z2[6], z2[7]);
    zp[2] = make_float4(z2[8], z2[9], z2[10], z2[11]);
    zp[3] = make_float4(z2[12], z2[13], z2[14], z2[15]);

    float sv[16], sq[16];
    #pragma unroll
    for (int k = 0; k < 16; ++k) { sv[k] = z2[k]; sq[k] = z2[k] * z2[k]; }
    #pragma unroll
    for (int m = 1; m < 64; m <<= 1) {
        #pragma unroll
        for (int k = 0; k < 16; ++k) {
            sv[k] += __shfl_xor(sv[k], m, 64);
            sq[k] += __shfl_xor(sq[k], m, 64);
        }
    }
    if (t == 0) {
        float* dst = acc2 + (blockIdx.x & 31) * 32;
        #pragma unroll
        for (int k = 0; k < 16; ++k) atomicAdd(dst + k, sv[k]);
        #pragma unroll
        for (int k = 0; k < 16; ++k) atomicAdd(dst + 16 + k, sq[k]);
    }
}

// ---------------------------------------------------------------------------
// k_out: BN2 + relu + layer3(relu) + layer4 + sigmoid.  (R0-verified)
// Grid: 128 x 64.
// ---------------------------------------------------------------------------
__global__ __launch_bounds__(64) void k_out(
        const float* __restrict__ z2ws, const float* __restrict__ acc2,
        const float* __restrict__ g2, const float* __restrict__ be2,
        const float* __restrict__ cW3, const float* __restrict__ cb3,
        const float* __restrict__ cW4, const float* __restrict__ cb4,
        float* __restrict__ out) {
    const int t = threadIdx.x;
    __shared__ float sB[32];
    __shared__ float m2s[16], is2[16];
    if (t < 32) {
        float s = 0.f;
        for (int sl = 0; sl < 32; ++sl) s += acc2[sl * 32 + t];
        sB[t] = s;
    }
    __syncthreads();
    if (t < 16) {
        const float m = sB[t] * INV_B;
        const float var = sB[16 + t] * INV_B - m * m;
        m2s[t] = m;
        is2[t] = 1.0f / sqrtf(var + 1e-5f);
    }
    __syncthreads();

    const long e = (long)blockIdx.x * 64 + t;
    const float4* zp = (const float4*)(z2ws + e * 16);
    const float4 v0 = zp[0], v1 = zp[1], v2 = zp[2], v3 = zp[3];
    const float z2[16] = {v0.x, v0.y, v0.z, v0.w, v1.x, v1.y, v1.z, v1.w,
                          v2.x, v2.y, v2.z, v2.w, v3.x, v3.y, v3.z, v3.w};
    float a2[16];
    #pragma unroll
    for (int k = 0; k < 16; ++k)
        a2[k] = fmaxf((z2[k] - m2s[k]) * is2[k] * g2[k] + be2[k], 0.f);
    float z3[8];
    #pragma unroll
    for (int j = 0; j < 8; ++j) {
        float s = cb3[j];
        #pragma unroll
        for (int k = 0; k < 16; ++k) s += cW3[j * 16 + k] * a2[k];
        z3[j] = fmaxf(s, 0.f);
    }
    float y = cb4[0];
    #pragma unroll
    for (int j = 0; j < 8; ++j) y += cW4[j] * z3[j];
    out[e] = 1.0f / (1.0f + expf(-y));
}

// ---------------------------------------------------------------------------
extern "C" void kernel_launch(void* const* d_in, const int* in_sizes, int n_in,
                              void* d_out, int out_size, void* d_ws, size_t ws_size,
                              hipStream_t stream) {
    (void)in_sizes; (void)n_in; (void)out_size; (void)ws_size;
    const float* x   = (const float*)d_in[0];
    const float* qw  = (const float*)d_in[1];
    const float* aW  = (const float*)d_in[2];
    const float* ab  = (const float*)d_in[3];
    const float* fW1 = (const float*)d_in[4];
    const float* fb1 = (const float*)d_in[5];
    const float* fW2 = (const float*)d_in[6];
    const float* fb2 = (const float*)d_in[7];
    const float* cW1 = (const float*)d_in[8];
    const float* cb1 = (const float*)d_in[9];
    const float* g1  = (const float*)d_in[10];
    const float* be1 = (const float*)d_in[11];
    const float* cW2 = (const float*)d_in[12];
    const float* cb2 = (const float*)d_in[13];
    const float* g2  = (const float*)d_in[14];
    const float* be2 = (const float*)d_in[15];
    const float* cW3 = (const float*)d_in[16];
    const float* cb3 = (const float*)d_in[17];
    const float* cW4 = (const float*)d_in[18];
    const float* cb4 = (const float*)d_in[19];

    float* ws   = (float*)d_ws;
    float* acc1 = ws;               // 32 slots x 20 = 640   (zeroed by k_pre)
    float* acc2 = ws + 1024;        // 32 slots x 32 = 1024  (zeroed by k_pre)
    float* U    = ws + 2048;        // 48 x 4
    float* fT   = ws + 4096;        // 16384 (fW1 transposed)
    float* hws  = ws + 24576;       // 8192 x 4
    float* z2ws = ws + 57344;       // 8192 x 16   (total ~736 KB)

    k_pre <<<64, 256, 0, stream>>>(fW1, qw, U, fT, ws);
    k_main<<<2048, 256, 0, stream>>>(x, U, fT, fb1, fW2, fb2, aW, ab, hws, acc1);
    k_mid <<<128, 64, 0, stream>>>(hws, acc1, cW1, cb1, g1, be1, cW2, cb2, z2ws, acc2);
    k_out <<<128, 64, 0, stream>>>(z2ws, acc2, g2, be2, cW3, cb3, cW4, cb4, (float*)d_out);
}

// Round 5
// 148.083 us; speedup vs baseline: 1.3020x; 1.0614x over previous
//
#include <hip/hip_runtime.h>
#include <math.h>

#define INV_B (1.0f / 8192.0f)

typedef float  v2f  __attribute__((ext_vector_type(2)));
typedef _Float16 half8 __attribute__((ext_vector_type(8)));
typedef float  f32x4 __attribute__((ext_vector_type(4)));

// ---------------------------------------------------------------------------
// Compile-time GF(2) tracking of the CNOT network (R3-verified, absmax 0.0).
// Index i (8 bits): wire w <-> bit (7-w).  Storage: i = 4*lane + reg.
// ---------------------------------------------------------------------------
struct QTables {
    int xm[6][8];   // xor (partner) mask per (layer, wire)
    int rm[6][8];   // row parity mask per (layer, wire)
    int meas[4];    // measurement parity masks, wires 0..3
};
constexpr QTables make_tables() {
    QTables T{};
    int Mrow[8] = {}, Ncol[8] = {};
    for (int b = 0; b < 8; ++b) { Mrow[b] = 1 << b; Ncol[b] = 1 << b; }
    constexpr int bc[11] = {7,6,5,4,3,2,1,0,7,5,3};
    constexpr int bt[11] = {6,5,4,3,2,1,0,7,5,3,1};
    for (int l = 0; l < 6; ++l) {
        for (int w = 0; w < 8; ++w) { T.xm[l][w] = Ncol[7 - w]; T.rm[l][w] = Mrow[7 - w]; }
        for (int k = 0; k < 11; ++k) { Mrow[bt[k]] ^= Mrow[bc[k]]; Ncol[bc[k]] ^= Ncol[bt[k]]; }
    }
    for (int w = 0; w < 4; ++w) T.meas[w] = Mrow[7 - w];
    return T;
}
constexpr QTables TB = make_tables();

// xor-shuffle along lane mask ML: 1..3 DPP quad_perm (VALU pipe),
// 4..31 ds_swizzle (LDS pipe, immediate offset), >=32 ds_bpermute.
template<int ML>
static __device__ __forceinline__ float lanex(float v) {
    if constexpr (ML == 0) { return v; }
    else if constexpr (ML == 1) { return __int_as_float(__builtin_amdgcn_update_dpp(0, __float_as_int(v), 0xB1, 0xF, 0xF, true)); }
    else if constexpr (ML == 2) { return __int_as_float(__builtin_amdgcn_update_dpp(0, __float_as_int(v), 0x4E, 0xF, 0xF, true)); }
    else if constexpr (ML == 3) { return __int_as_float(__builtin_amdgcn_update_dpp(0, __float_as_int(v), 0x1B, 0xF, 0xF, true)); }
    else if constexpr (ML < 32) { return __int_as_float(__builtin_amdgcn_ds_swizzle(__float_as_int(v), 0x1F | (ML << 10))); }
    else { return __shfl_xor(v, ML, 64); }
}

static __device__ __forceinline__ float bsum64(float v) {
    v += lanex<1>(v);  v += lanex<2>(v);
    v += lanex<4>(v);  v += lanex<8>(v);
    v += lanex<16>(v); v += __shfl_xor(v, 32, 64);
    return v;
}

static __device__ __forceinline__ float tanh_fast(float v) {
    const float c = fminf(fmaxf(v, -10.f), 10.f);
    const float e = __expf(2.f * c);
    return (e - 1.f) / (e + 1.f);
}

// Fused SU(2) gate, packed complex: z = (re, im).
// new = u00r*z + csi*(-z.y,z.x) + cpr*p + u01i*(-p.y,p.x)
template<int XM, int RM>
static __device__ __forceinline__ void gate(v2f (&z)[4], const int lane,
                                            const float u00r, const float u00i,
                                            const float u01r, const float u01i) {
    constexpr int ML = XM >> 2, MR = XM & 3;
    constexpr int RL = RM >> 2, RR = RM & 3;
    const int pl = __popc(lane & RL) & 1;
    const float csi0 = pl ? -u00i : u00i;
    const float cpr0 = pl ? -u01r : u01r;
    const float csi1 = -csi0, cpr1 = -cpr0;
    v2f p[4];
    #pragma unroll
    for (int r = 0; r < 4; ++r) {
        p[r].x = lanex<ML>(z[r ^ MR].x);
        p[r].y = lanex<ML>(z[r ^ MR].y);
    }
    #pragma unroll
    for (int r = 0; r < 4; ++r) {
        const int pb = __builtin_popcount(r & RR) & 1;   // folds at compile time
        const float csi = pb ? csi1 : csi0;
        const float cpr = pb ? cpr1 : cpr0;
        const v2f zs = { -z[r].y, z[r].x };
        const v2f ps = { -p[r].y, p[r].x };
        z[r] = ((u00r * z[r] + csi * zs) + cpr * p[r]) + u01i * ps;
    }
}

// ---------------------------------------------------------------------------
// k_feat: cf = tanh(relu(x@fW1.T+fb1)@fW2.T+fb2) via MFMA f16 16x16x32
// (fp32 accum).  Also builds the 48 fused unitaries (block 0) and zeros the
// BN accumulators.  Grid: 128 blocks x 256 thr; block = 64 batch rows;
// wave = 16 rows (one 16-wide n-tile), 4 j-tiles of 16.
// Frag maps (guide-verified): A[m=lane&15][k=quad*8+j]; B[k=quad*8+j][n=lane&15];
// D col=lane&15 (n), row=quad*4+r (m).
// ---------------------------------------------------------------------------
#define XS 264   // padded LDS stride in halves (264*2B = 528B, 16B-divisible)
__global__ __launch_bounds__(256) void k_feat(
        const float* __restrict__ x, const float* __restrict__ qw,
        const float* __restrict__ fW1, const float* __restrict__ fb1,
        const float* __restrict__ fW2, const float* __restrict__ fb2,
        float* __restrict__ U, float* __restrict__ cfws, float* __restrict__ accz) {
    const int t = threadIdx.x, b = blockIdx.x;

    if (t < 16) accz[b * 16 + t] = 0.f;          // 128*16 = 2048 floats (acc1+acc2)
    if (b == 0 && t < 48) {
        const int l = t >> 3, q = t & 7;
        const float* a = qw + l * 24 + q * 3;
        const float h1 = 0.5f * a[0], h2 = 0.5f * a[1], h3 = 0.5f * a[2];
        const float c1 = cosf(h1), s1 = sinf(h1);
        const float c2 = cosf(h2), s2 = sinf(h2);
        const float c3 = cosf(h3), s3 = sinf(h3);
        const float m00r =  c1 * c2, m00i =  s1 * s2;   // (Ry*Rx) row 0
        const float m01r = -c1 * s2, m01i = -s1 * c2;
        float4 u;
        u.x = m00r * c3 + m00i * s3;  u.y = m00i * c3 - m00r * s3;   // u00 e^{-i h3}
        u.z = m01r * c3 + m01i * s3;  u.w = m01i * c3 - m01r * s3;   // u01 e^{-i h3}
        ((float4*)U)[t] = u;
    }

    __shared__ _Float16 xl[64 * XS];   // x tile (rows = batch), f16
    __shared__ _Float16 wl[64 * XS];   // fW1 (rows = j), f16
    const long r0 = (long)b * 64;
    #pragma unroll
    for (int i = 0; i < 16; ++i) {
        const int idx = i * 256 + t;           // 4096 float4 tiles
        const int row = idx >> 6, c4 = idx & 63;
        const float4 xv = ((const float4*)(x + (r0 + row) * 256))[c4];
        _Float16* d = &xl[row * XS + c4 * 4];
        d[0] = (_Float16)xv.x; d[1] = (_Float16)xv.y;
        d[2] = (_Float16)xv.z; d[3] = (_Float16)xv.w;
        const float4 wv = ((const float4*)(fW1 + (long)row * 256))[c4];
        _Float16* e = &wl[row * XS + c4 * 4];
        e[0] = (_Float16)wv.x; e[1] = (_Float16)wv.y;
        e[2] = (_Float16)wv.z; e[3] = (_Float16)wv.w;
    }
    __syncthreads();

    const int lane = t & 63, w4 = t >> 6;
    const int g = lane >> 4, col = lane & 15;
    const int rloc = w4 * 16 + col;            // local batch row (B-frag n-index)

    half8 bf[8];                               // B frags: k = kb*32 + g*8 + jj
    #pragma unroll
    for (int kb = 0; kb < 8; ++kb)
        bf[kb] = *(const half8*)&xl[rloc * XS + kb * 32 + g * 8];

    float accc[4] = {0.f, 0.f, 0.f, 0.f};
    #pragma unroll
    for (int jc = 0; jc < 4; ++jc) {
        f32x4 cv = {0.f, 0.f, 0.f, 0.f};
        #pragma unroll
        for (int kb = 0; kb < 8; ++kb) {
            // A frag: m = col (j within tile jc), k = kb*32 + g*8 + jj
            const half8 af = *(const half8*)&wl[(jc * 16 + col) * XS + kb * 32 + g * 8];
            cv = __builtin_amdgcn_mfma_f32_16x16x32_f16(af, bf[kb], cv, 0, 0, 0);
        }
        // D frag: col = batch row (lane&15), row m = g*4 + r -> j = jc*16 + g*4 + r
        #pragma unroll
        for (int r = 0; r < 4; ++r) {
            const int j = jc * 16 + g * 4 + r;
            const float z = fmaxf(cv[r] + fb1[j], 0.f);
            #pragma unroll
            for (int c = 0; c < 4; ++c) accc[c] += z * fW2[c * 64 + j];
        }
    }
    #pragma unroll
    for (int c = 0; c < 4; ++c) {              // reduce over g (j-groups)
        accc[c] += __shfl_xor(accc[c], 16, 64);
        accc[c] += __shfl_xor(accc[c], 32, 64);
    }
    if (g == 0) {
        float4 o;
        o.x = tanh_fast(accc[0] + fb2[0]);
        o.y = tanh_fast(accc[1] + fb2[1]);
        o.z = tanh_fast(accc[2] + fb2[2]);
        o.w = tanh_fast(accc[3] + fb2[3]);
        ((float4*)cfws)[r0 + w4 * 16 + col] = o;
    }
}

// ---------------------------------------------------------------------------
// k_main: quantum circuit (packed complex) + h + BN1 moment atomics.
// One wave per batch row; 2048 blocks x 256 thr.
// ---------------------------------------------------------------------------
__global__ __launch_bounds__(256) void k_main(
        const float* __restrict__ x, const float* __restrict__ U,
        const float* __restrict__ cfws,
        const float* __restrict__ aW, const float* __restrict__ ab,
        float* __restrict__ hws, float* __restrict__ acc1) {
    const int t = threadIdx.x, lane = t & 63, wv = t >> 6;
    const int b = blockIdx.x;
    const int row = b * 4 + wv;

    const float4 xr = ((const float4*)(x + (long)row * 256))[lane];

    v2f z[4] = { {xr.x, 0.f}, {xr.y, 0.f}, {xr.z, 0.f}, {xr.w, 0.f} };
    const float4* U4 = (const float4*)U;

#define GATE(L, W) { const float4 u = U4[(L) * 8 + (W)]; \
                     gate<TB.xm[L][W], TB.rm[L][W]>(z, lane, u.x, u.y, u.z, u.w); }
#define LAYER(L) GATE(L,0) GATE(L,1) GATE(L,2) GATE(L,3) GATE(L,4) GATE(L,5) GATE(L,6) GATE(L,7)
    LAYER(0) LAYER(1) LAYER(2) LAYER(3) LAYER(4) LAYER(5)
#undef LAYER
#undef GATE

    float pv[4];
    #pragma unroll
    for (int r = 0; r < 4; ++r) pv[r] = z[r].x * z[r].x + z[r].y * z[r].y;
    float S = pv[0] + pv[1] + pv[2] + pv[3];
    float qs[4];
    #pragma unroll
    for (int w = 0; w < 4; ++w) {
        const int mm = TB.meas[w];
        const int plm = __popc(lane & (mm >> 2)) & 1;
        float s = 0.f;
        #pragma unroll
        for (int r = 0; r < 4; ++r) {
            const int sgn = plm ^ (__builtin_popcount(r & (mm & 3)) & 1);
            s += sgn ? -pv[r] : pv[r];
        }
        qs[w] = s;
    }
    S = bsum64(S);
    const float inv = 1.0f / S;                // folds AmplitudeEmbedding norm
    float qe[4];
    #pragma unroll
    for (int w = 0; w < 4; ++w) qe[w] = bsum64(qs[w]) * inv;

    const float4 cfv = ((const float4*)cfws)[row];
    const float cf[4] = {cfv.x, cfv.y, cfv.z, cfv.w};
    float h[4];
    #pragma unroll
    for (int k = 0; k < 4; ++k) {
        float s = ab[k] + cf[k];
        #pragma unroll
        for (int j = 0; j < 4; ++j) s += aW[k * 4 + j] * qe[j];
        h[k] = s;
    }
    if (lane == 0)
        ((float4*)hws)[row] = make_float4(h[0], h[1], h[2], h[3]);

    __shared__ float wsum[4][20];
    if (lane == 0) {
        #pragma unroll
        for (int k = 0; k < 4; ++k) wsum[wv][k] = h[k];
        #pragma unroll
        for (int j = 0; j < 4; ++j)
            #pragma unroll
            for (int k = 0; k < 4; ++k) wsum[wv][4 + j * 4 + k] = h[j] * h[k];
    }
    __syncthreads();
    if (t < 20)
        atomicAdd(acc1 + (b & 31) * 20 + t,
                  wsum[0][t] + wsum[1][t] + wsum[2][t] + wsum[3][t]);
}

// ---------------------------------------------------------------------------
// k_mid: analytic BN1 + relu + layer2 -> z2; z2 batch stats.  (R0-verified)
// ---------------------------------------------------------------------------
__global__ __launch_bounds__(64) void k_mid(
        const float* __restrict__ hws, const float* __restrict__ acc1,
        const float* __restrict__ cW1, const float* __restrict__ cb1,
        const float* __restrict__ g1, const float* __restrict__ be1,
        const float* __restrict__ cW2, const float* __restrict__ cb2,
        float* __restrict__ z2ws, float* __restrict__ acc2) {
    const int t = threadIdx.x;
    __shared__ float sA[20];
    __shared__ float m1s[32], is1[32];
    if (t < 20) {
        float s = 0.f;
        for (int sl = 0; sl < 32; ++sl) s += acc1[sl * 20 + t];
        sA[t] = s;
    }
    __syncthreads();
    if (t < 32) {
        float mu[4], w[4];
        #pragma unroll
        for (int k = 0; k < 4; ++k) mu[k] = sA[k] * INV_B;
        float m = cb1[t];
        #pragma unroll
        for (int k = 0; k < 4; ++k) { w[k] = cW1[t * 4 + k]; m += w[k] * mu[k]; }
        float var = 0.f;
        #pragma unroll
        for (int a2 = 0; a2 < 4; ++a2)
            #pragma unroll
            for (int b2 = 0; b2 < 4; ++b2)
                var += w[a2] * w[b2] * (sA[4 + a2 * 4 + b2] * INV_B - mu[a2] * mu[b2]);
        m1s[t] = m;
        is1[t] = 1.0f / sqrtf(var + 1e-5f);
    }
    __syncthreads();

    const long e = (long)blockIdx.x * 64 + t;
    const float4 h4 = ((const float4*)hws)[e];
    const float h[4] = {h4.x, h4.y, h4.z, h4.w};
    float a1[32];
    #pragma unroll
    for (int j = 0; j < 32; ++j) {
        float zz = cb1[j];
        #pragma unroll
        for (int k = 0; k < 4; ++k) zz += cW1[j * 4 + k] * h[k];
        a1[j] = fmaxf((zz - m1s[j]) * is1[j] * g1[j] + be1[j], 0.f);
    }
    float z2[16];
    #pragma unroll
    for (int k = 0; k < 16; ++k) {
        float s = cb2[k];
        #pragma unroll
        for (int j = 0; j < 32; ++j) s += cW2[k * 32 + j] * a1[j];
        z2[k] = s;
    }
    float4* zp = (float4*)(z2ws + e * 16);
    zp[0] = make_float4(z2[0], z2[1], z2[2], z2[3]);
    zp[1] = make_float4(z2[4], z2[5], z2[6], z2[7]);
    zp[2] = make_float4(z2[8], z2[9], z2[10], z2[11]);
    zp[3] = make_float4(z2[12], z2[13], z2[14], z2[15]);

    float sv[16], sq[16];
    #pragma unroll
    for (int k = 0; k < 16; ++k) { sv[k] = z2[k]; sq[k] = z2[k] * z2[k]; }
    #pragma unroll
    for (int m = 1; m < 64; m <<= 1) {
        #pragma unroll
        for (int k = 0; k < 16; ++k) {
            sv[k] += __shfl_xor(sv[k], m, 64);
            sq[k] += __shfl_xor(sq[k], m, 64);
        }
    }
    if (t == 0) {
        float* dst = acc2 + (blockIdx.x & 31) * 32;
        #pragma unroll
        for (int k = 0; k < 16; ++k) atomicAdd(dst + k, sv[k]);
        #pragma unroll
        for (int k = 0; k < 16; ++k) atomicAdd(dst + 16 + k, sq[k]);
    }
}

// ---------------------------------------------------------------------------
// k_out: BN2 + relu + layer3(relu) + layer4 + sigmoid.  (R0-verified)
// ---------------------------------------------------------------------------
__global__ __launch_bounds__(64) void k_out(
        const float* __restrict__ z2ws, const float* __restrict__ acc2,
        const float* __restrict__ g2, const float* __restrict__ be2,
        const float* __restrict__ cW3, const float* __restrict__ cb3,
        const float* __restrict__ cW4, const float* __restrict__ cb4,
        float* __restrict__ out) {
    const int t = threadIdx.x;
    __shared__ float sB[32];
    __shared__ float m2s[16], is2[16];
    if (t < 32) {
        float s = 0.f;
        for (int sl = 0; sl < 32; ++sl) s += acc2[sl * 32 + t];
        sB[t] = s;
    }
    __syncthreads();
    if (t < 16) {
        const float m = sB[t] * INV_B;
        const float var = sB[16 + t] * INV_B - m * m;
        m2s[t] = m;
        is2[t] = 1.0f / sqrtf(var + 1e-5f);
    }
    __syncthreads();

    const long e = (long)blockIdx.x * 64 + t;
    const float4* zp = (const float4*)(z2ws + e * 16);
    const float4 v0 = zp[0], v1 = zp[1], v2 = zp[2], v3 = zp[3];
    const float z2[16] = {v0.x, v0.y, v0.z, v0.w, v1.x, v1.y, v1.z, v1.w,
                          v2.x, v2.y, v2.z, v2.w, v3.x, v3.y, v3.z, v3.w};
    float a2[16];
    #pragma unroll
    for (int k = 0; k < 16; ++k)
        a2[k] = fmaxf((z2[k] - m2s[k]) * is2[k] * g2[k] + be2[k], 0.f);
    float z3[8];
    #pragma unroll
    for (int j = 0; j < 8; ++j) {
        float s = cb3[j];
        #pragma unroll
        for (int k = 0; k < 16; ++k) s += cW3[j * 16 + k] * a2[k];
        z3[j] = fmaxf(s, 0.f);
    }
    float y = cb4[0];
    #pragma unroll
    for (int j = 0; j < 8; ++j) y += cW4[j] * z3[j];
    out[e] = 1.0f / (1.0f + expf(-y));
}

// ---------------------------------------------------------------------------
extern "C" void kernel_launch(void* const* d_in, const int* in_sizes, int n_in,
                              void* d_out, int out_size, void* d_ws, size_t ws_size,
                              hipStream_t stream) {
    (void)in_sizes; (void)n_in; (void)out_size; (void)ws_size;
    const float* x   = (const float*)d_in[0];
    const float* qw  = (const float*)d_in[1];
    const float* aW  = (const float*)d_in[2];
    const float* ab  = (const float*)d_in[3];
    const float* fW1 = (const float*)d_in[4];
    const float* fb1 = (const float*)d_in[5];
    const float* fW2 = (const float*)d_in[6];
    const float* fb2 = (const float*)d_in[7];
    const float* cW1 = (const float*)d_in[8];
    const float* cb1 = (const float*)d_in[9];
    const float* g1  = (const float*)d_in[10];
    const float* be1 = (const float*)d_in[11];
    const float* cW2 = (const float*)d_in[12];
    const float* cb2 = (const float*)d_in[13];
    const float* g2  = (const float*)d_in[14];
    const float* be2 = (const float*)d_in[15];
    const float* cW3 = (const float*)d_in[16];
    const float* cb3 = (const float*)d_in[17];
    const float* cW4 = (const float*)d_in[18];
    const float* cb4 = (const float*)d_in[19];

    float* ws   = (float*)d_ws;
    float* acc1 = ws;               // 32 slots x 20 = 640   (zeroed by k_feat)
    float* acc2 = ws + 1024;        // 32 slots x 32 = 1024  (zeroed by k_feat)
    float* U    = ws + 2048;        // 48 x 4
    float* cfws = ws + 4096;        // 8192 x 4
    float* hws  = ws + 40960;       // 8192 x 4
    float* z2ws = ws + 81920;       // 8192 x 16

    k_feat<<<128, 256, 0, stream>>>(x, qw, fW1, fb1, fW2, fb2, U, cfws, ws);
    k_main<<<2048, 256, 0, stream>>>(x, U, cfws, aW, ab, hws, acc1);
    k_mid <<<128, 64, 0, stream>>>(hws, acc1, cW1, cb1, g1, be1, cW2, cb2, z2ws, acc2);
    k_out <<<128, 64, 0, stream>>>(z2ws, acc2, g2, be2, cW3, cb3, cW4, cb4, (float*)d_out);
}